// Round 14
// baseline (108.809 us; speedup 1.0000x reference)
//
#include <hip/hip_runtime.h>
#include <math.h>

namespace {
constexpr int B_ = 4096;
constexpr int C_ = 12288;
constexpr int R_ = 2;                    // rows per block
constexpr float DEG2RAD = 0.017453292519943295f;
constexpr float LOG2E = 1.4426950408889634f;
// w = exp(-2R*asin(s)/tau) = exp2(KN2*asin(s)), KN2 = -(2*6371/75)*log2(e)
constexpr float KN2 = -245.10427f;
// asin(s) ~= s*(1 + a/6), a = s^2. Truncation ~1e-5 in the exponent where w
// matters -> invisible. KN2*asin(s) = s*(C0 + C1*a).
constexpr float C0 = KN2;
constexpr float C1 = KN2 / 6.0f;
typedef float f32x2 __attribute__((ext_vector_type(2)));
}

// Per-centroid HALF unit-sphere coords, interleaved per 4-centroid group:
// group g occupies 12 floats: [x0..x3][y0..y3][z0..z3] -> one address stream.
// Thread 0 zeroes the completion counter used by the fused final reduction.
__global__ void centroid_xyz_kernel(const float* __restrict__ centroids,
                                    float* __restrict__ ctq,
                                    int* __restrict__ counter) {
    int c = blockIdx.x * blockDim.x + threadIdx.x;
    if (c == 0) *counter = 0;
    if (c >= C_) return;
    float lat = centroids[2 * c] * DEG2RAD;
    float lon = centroids[2 * c + 1] * DEG2RAD;
    float sl = __sinf(lat), cl = __cosf(lat);   // native: ~1e-7 rad err -> ~0.01 km
    float sn = __sinf(lon), cn = __cosf(lon);
    int g = c >> 2, j = c & 3;
    ctq[12 * g + j]     = 0.5f * cl * cn;
    ctq[12 * g + 4 + j] = 0.5f * cl * sn;
    ctq[12 * g + 8 + j] = 0.5f * sl;
}

__device__ __forceinline__ float wave_red_add(float v) {
#pragma unroll
    for (int off = 32; off > 0; off >>= 1) v += __shfl_down(v, off, 64);
    return v;
}

// Two pairs per call as f32x2: regular ops pack into VOP3P (2 fp32/inst);
// sqrt/exp2 have no packed form and stay scalar.
__device__ __forceinline__ void accum_pair2(f32x2 l2, f32x2 x2, f32x2 y2,
                                            f32x2 z2, float x1, float y1,
                                            float z1, f32x2& W, f32x2& T,
                                            f32x2& S) {
    f32x2 dx = x2 - x1, dy = y2 - y1, dz = z2 - z1;
    f32x2 a = dx * dx + dy * dy + dz * dz;           // = sin^2(theta/2)
    f32x2 s;
    s.x = __builtin_amdgcn_sqrtf(a.x);
    s.y = __builtin_amdgcn_sqrtf(a.y);
    f32x2 p = a * C1 + C0;
    f32x2 e = s * p;
    f32x2 w;
    w.x = __builtin_amdgcn_exp2f(e.x);
    w.y = __builtin_amdgcn_exp2f(e.y);
    W += w;
    T += w * l2;
    f32x2 le = l2 * LOG2E;
    f32x2 el;
    el.x = __builtin_amdgcn_exp2f(le.x);
    el.y = __builtin_amdgcn_exp2f(le.y);
    S += el;
}

// One block per R_ rows. Main loop identical to round 13 (best). Fused final
// reduction: every block bumps `counter` after its fenced row_loss writes;
// the last block sums all B_ losses (agent-scope loads to dodge stale XCD-L2
// copies left by the harness poison fill) and writes out[0]. Reduction order
// is fixed -> deterministic output regardless of which block is last.
__global__ __launch_bounds__(256) void row_loss_kernel(
    const float* __restrict__ logits, const float* __restrict__ latlon,
    const float* __restrict__ ctq, float* __restrict__ row_loss,
    int* __restrict__ counter, float* __restrict__ out) {
    const int b0 = blockIdx.x * R_;

    float x1[R_], y1[R_], z1[R_];
#pragma unroll
    for (int r = 0; r < R_; ++r) {
        float lat = latlon[2 * (b0 + r)] * DEG2RAD;
        float lon = latlon[2 * (b0 + r) + 1] * DEG2RAD;
        float cl = cosf(lat);
        x1[r] = 0.5f * cl * cosf(lon);
        y1[r] = 0.5f * cl * sinf(lon);
        z1[r] = 0.5f * sinf(lat);
    }

    const float4* __restrict__ ct4 = (const float4*)ctq + 3 * (size_t)threadIdx.x;
    const float4* __restrict__ L0 =
        (const float4*)(logits + (size_t)b0 * C_) + threadIdx.x;
    const float4* __restrict__ L1 =
        (const float4*)(logits + (size_t)(b0 + 1) * C_) + threadIdx.x;

    f32x2 W[R_], T[R_], S[R_];
#pragma unroll
    for (int r = 0; r < R_; ++r) {
        W[r] = (f32x2)(0.f);
        T[r] = (f32x2)(0.f);
        S[r] = (f32x2)(0.f);
    }

#pragma unroll 2
    for (int i = 0; i < C_ / 4 / 256; ++i) {
        float4 X = ct4[0];
        float4 Y = ct4[1];
        float4 Z = ct4[2];
        float4 la = *L0;
        float4 lb = *L1;
        f32x2 X0 = {X.x, X.y}, X1v = {X.z, X.w};
        f32x2 Y0 = {Y.x, Y.y}, Y1v = {Y.z, Y.w};
        f32x2 Z0 = {Z.x, Z.y}, Z1v = {Z.z, Z.w};
        f32x2 la0 = {la.x, la.y}, la1 = {la.z, la.w};
        f32x2 lb0 = {lb.x, lb.y}, lb1 = {lb.z, lb.w};
        accum_pair2(la0, X0, Y0, Z0, x1[0], y1[0], z1[0], W[0], T[0], S[0]);
        accum_pair2(la1, X1v, Y1v, Z1v, x1[0], y1[0], z1[0], W[0], T[0], S[0]);
        accum_pair2(lb0, X0, Y0, Z0, x1[1], y1[1], z1[1], W[1], T[1], S[1]);
        accum_pair2(lb1, X1v, Y1v, Z1v, x1[1], y1[1], z1[1], W[1], T[1], S[1]);
        ct4 += 3 * 256;
        L0 += 256;
        L1 += 256;
    }

    __shared__ float red[3][R_][4];
    __shared__ float red2[4];
    __shared__ int lastFlag;
    const int lane = threadIdx.x & 63, wv = threadIdx.x >> 6;
#pragma unroll
    for (int r = 0; r < R_; ++r) {
        float Wr = wave_red_add(W[r].x + W[r].y);
        float Tr = wave_red_add(T[r].x + T[r].y);
        float Sr = wave_red_add(S[r].x + S[r].y);
        if (lane == 0) { red[0][r][wv] = Wr; red[1][r][wv] = Tr; red[2][r][wv] = Sr; }
    }
    __syncthreads();
    if (threadIdx.x < R_) {
        int r = threadIdx.x;
        float Wt = red[0][r][0] + red[0][r][1] + red[0][r][2] + red[0][r][3];
        float Tt = red[1][r][0] + red[1][r][1] + red[1][r][2] + red[1][r][3];
        float St = red[2][r][0] + red[2][r][1] + red[2][r][2] + red[2][r][3];
        Wt = fmaxf(Wt, 1e-30f);
        row_loss[b0 + r] = logf(St) - Tt / Wt;
    }

    __syncthreads();   // row_loss stores drained (vmcnt 0 before barrier)
    if (threadIdx.x == 0) {
        __threadfence();   // writeback to device scope before signaling
        int v = atomicAdd(counter, 1);
        lastFlag = (v == (int)gridDim.x - 1);
    }
    __syncthreads();
    if (lastFlag) {
        float s = 0.f;
        for (int i = threadIdx.x; i < B_; i += 256)
            s += __hip_atomic_load(&row_loss[i], __ATOMIC_RELAXED,
                                   __HIP_MEMORY_SCOPE_AGENT);
        s = wave_red_add(s);
        if (lane == 0) red2[wv] = s;
        __syncthreads();
        if (threadIdx.x == 0)
            out[0] = (red2[0] + red2[1] + red2[2] + red2[3]) * (1.0f / B_);
    }
}

extern "C" void kernel_launch(void* const* d_in, const int* in_sizes, int n_in,
                              void* d_out, int out_size, void* d_ws, size_t ws_size,
                              hipStream_t stream) {
    const float* pred_logits = (const float*)d_in[0];  // [B, C] f32
    const float* latlon      = (const float*)d_in[1];  // [B, 2] f32
    const float* centroids   = (const float*)d_in[2];  // [C, 2] f32
    // d_in[3] geocell_indices is unused by the reference.
    float* ctq      = (float*)d_ws;          // 3*C floats, interleaved quads
    float* row_loss = ctq + 3 * C_;          // B floats
    int*   counter  = (int*)(row_loss + B_); // completion counter
    float* out      = (float*)d_out;

    centroid_xyz_kernel<<<(C_ + 255) / 256, 256, 0, stream>>>(centroids, ctq,
                                                              counter);
    row_loss_kernel<<<B_ / R_, 256, 0, stream>>>(pred_logits, latlon, ctq,
                                                 row_loss, counter, out);
}

// Round 15
// 42.561 us; speedup vs baseline: 2.5566x; 2.5566x over previous
//
#include <hip/hip_runtime.h>
#include <math.h>

namespace {
constexpr int B_ = 4096;
constexpr int C_ = 12288;
constexpr int R_ = 2;                    // rows per block
constexpr float DEG2RAD = 0.017453292519943295f;
constexpr float LOG2E = 1.4426950408889634f;
// w = exp(-2R*asin(s)/tau) = exp2(KN2*asin(s)), KN2 = -(2*6371/75)*log2(e)
constexpr float KN2 = -245.10427f;
// asin(s) ~= s*(1 + a/6), a = s^2. Truncation ~1e-5 in the exponent where w
// matters -> invisible. KN2*asin(s) = s*(C0 + C1*a).
constexpr float C0 = KN2;
constexpr float C1 = KN2 / 6.0f;
typedef float f32x2 __attribute__((ext_vector_type(2)));
}

// Per-centroid HALF unit-sphere coords, interleaved per 4-centroid group:
// group g occupies 12 floats: [x0..x3][y0..y3][z0..z3] -> one address stream.
__global__ void centroid_xyz_kernel(const float* __restrict__ centroids,
                                    float* __restrict__ ctq) {
    int c = blockIdx.x * blockDim.x + threadIdx.x;
    if (c >= C_) return;
    float lat = centroids[2 * c] * DEG2RAD;
    float lon = centroids[2 * c + 1] * DEG2RAD;
    float sl = __sinf(lat), cl = __cosf(lat);  // native: ~1e-7 err -> ~0.01 km
    float sn = __sinf(lon), cn = __cosf(lon);
    int g = c >> 2, j = c & 3;
    ctq[12 * g + j]     = 0.5f * cl * cn;
    ctq[12 * g + 4 + j] = 0.5f * cl * sn;
    ctq[12 * g + 8 + j] = 0.5f * sl;
}

__device__ __forceinline__ float wave_red_add(float v) {
#pragma unroll
    for (int off = 32; off > 0; off >>= 1) v += __shfl_down(v, off, 64);
    return v;
}

// Two pairs per call as f32x2: regular ops pack into VOP3P (2 fp32/inst);
// sqrt/exp2 have no packed form and stay scalar.
__device__ __forceinline__ void accum_pair2(f32x2 l2, f32x2 x2, f32x2 y2,
                                            f32x2 z2, float x1, float y1,
                                            float z1, f32x2& W, f32x2& T,
                                            f32x2& S) {
    f32x2 dx = x2 - x1, dy = y2 - y1, dz = z2 - z1;
    f32x2 a = dx * dx + dy * dy + dz * dz;           // = sin^2(theta/2)
    f32x2 s;
    s.x = __builtin_amdgcn_sqrtf(a.x);
    s.y = __builtin_amdgcn_sqrtf(a.y);
    f32x2 p = a * C1 + C0;
    f32x2 e = s * p;
    f32x2 w;
    w.x = __builtin_amdgcn_exp2f(e.x);
    w.y = __builtin_amdgcn_exp2f(e.y);
    W += w;
    T += w * l2;
    f32x2 le = l2 * LOG2E;
    f32x2 el;
    el.x = __builtin_amdgcn_exp2f(le.x);
    el.y = __builtin_amdgcn_exp2f(le.y);
    S += el;
}

// One block per R_ rows; per 4-centroid group: 3 ct dwordx4 (one stream) +
// R_ logits dwordx4; math runs 2 pairs/lane packed. (Round-13 structure —
// the session best. Fence-fusion and atomic-fusion both measured-negative.)
__global__ __launch_bounds__(256) void row_loss_kernel(
    const float* __restrict__ logits, const float* __restrict__ latlon,
    const float* __restrict__ ctq, float* __restrict__ row_loss) {
    const int b0 = blockIdx.x * R_;

    float x1[R_], y1[R_], z1[R_];
#pragma unroll
    for (int r = 0; r < R_; ++r) {
        float lat = latlon[2 * (b0 + r)] * DEG2RAD;
        float lon = latlon[2 * (b0 + r) + 1] * DEG2RAD;
        float cl = cosf(lat);
        x1[r] = 0.5f * cl * cosf(lon);
        y1[r] = 0.5f * cl * sinf(lon);
        z1[r] = 0.5f * sinf(lat);
    }

    const float4* __restrict__ ct4 = (const float4*)ctq + 3 * (size_t)threadIdx.x;
    const float4* __restrict__ L0 =
        (const float4*)(logits + (size_t)b0 * C_) + threadIdx.x;
    const float4* __restrict__ L1 =
        (const float4*)(logits + (size_t)(b0 + 1) * C_) + threadIdx.x;

    f32x2 W[R_], T[R_], S[R_];
#pragma unroll
    for (int r = 0; r < R_; ++r) {
        W[r] = (f32x2)(0.f);
        T[r] = (f32x2)(0.f);
        S[r] = (f32x2)(0.f);
    }

#pragma unroll 2
    for (int i = 0; i < C_ / 4 / 256; ++i) {
        float4 X = ct4[0];
        float4 Y = ct4[1];
        float4 Z = ct4[2];
        float4 la = *L0;
        float4 lb = *L1;
        f32x2 X0 = {X.x, X.y}, X1v = {X.z, X.w};
        f32x2 Y0 = {Y.x, Y.y}, Y1v = {Y.z, Y.w};
        f32x2 Z0 = {Z.x, Z.y}, Z1v = {Z.z, Z.w};
        f32x2 la0 = {la.x, la.y}, la1 = {la.z, la.w};
        f32x2 lb0 = {lb.x, lb.y}, lb1 = {lb.z, lb.w};
        accum_pair2(la0, X0, Y0, Z0, x1[0], y1[0], z1[0], W[0], T[0], S[0]);
        accum_pair2(la1, X1v, Y1v, Z1v, x1[0], y1[0], z1[0], W[0], T[0], S[0]);
        accum_pair2(lb0, X0, Y0, Z0, x1[1], y1[1], z1[1], W[1], T[1], S[1]);
        accum_pair2(lb1, X1v, Y1v, Z1v, x1[1], y1[1], z1[1], W[1], T[1], S[1]);
        ct4 += 3 * 256;
        L0 += 256;
        L1 += 256;
    }

    __shared__ float red[3][R_][4];
    const int lane = threadIdx.x & 63, wv = threadIdx.x >> 6;
#pragma unroll
    for (int r = 0; r < R_; ++r) {
        float Wr = wave_red_add(W[r].x + W[r].y);
        float Tr = wave_red_add(T[r].x + T[r].y);
        float Sr = wave_red_add(S[r].x + S[r].y);
        if (lane == 0) { red[0][r][wv] = Wr; red[1][r][wv] = Tr; red[2][r][wv] = Sr; }
    }
    __syncthreads();
    if (threadIdx.x < R_) {
        int r = threadIdx.x;
        float Wt = red[0][r][0] + red[0][r][1] + red[0][r][2] + red[0][r][3];
        float Tt = red[1][r][0] + red[1][r][1] + red[1][r][2] + red[1][r][3];
        float St = red[2][r][0] + red[2][r][1] + red[2][r][2] + red[2][r][3];
        Wt = fmaxf(Wt, 1e-30f);
        row_loss[b0 + r] = logf(St) - Tt / Wt;
    }
}

// 1024 threads, one float4 load per thread covers all B_ losses in one shot.
__global__ __launch_bounds__(1024) void final_reduce_kernel(
    const float* __restrict__ row_loss, float* __restrict__ out) {
    const float4* __restrict__ rl4 = (const float4*)row_loss;
    float4 v = rl4[threadIdx.x];
    float s = (v.x + v.y) + (v.z + v.w);
    s = wave_red_add(s);
    __shared__ float red[16];
    const int lane = threadIdx.x & 63, wv = threadIdx.x >> 6;
    if (lane == 0) red[wv] = s;
    __syncthreads();
    if (threadIdx.x == 0) {
        float t = 0.f;
#pragma unroll
        for (int i = 0; i < 16; ++i) t += red[i];
        out[0] = t * (1.0f / B_);
    }
}

extern "C" void kernel_launch(void* const* d_in, const int* in_sizes, int n_in,
                              void* d_out, int out_size, void* d_ws, size_t ws_size,
                              hipStream_t stream) {
    const float* pred_logits = (const float*)d_in[0];  // [B, C] f32
    const float* latlon      = (const float*)d_in[1];  // [B, 2] f32
    const float* centroids   = (const float*)d_in[2];  // [C, 2] f32
    // d_in[3] geocell_indices is unused by the reference.
    float* ctq      = (float*)d_ws;      // 3*C floats, interleaved quads
    float* row_loss = ctq + 3 * C_;      // B floats
    float* out      = (float*)d_out;

    centroid_xyz_kernel<<<(C_ + 255) / 256, 256, 0, stream>>>(centroids, ctq);
    row_loss_kernel<<<B_ / R_, 256, 0, stream>>>(pred_logits, latlon, ctq, row_loss);
    final_reduce_kernel<<<1, 1024, 0, stream>>>(row_loss, out);
}